// Round 3
// baseline (2159.322 us; speedup 1.0000x reference)
//
#include <hip/hip_runtime.h>

typedef unsigned short u16;
typedef unsigned int u32;
typedef __attribute__((ext_vector_type(8))) short short8;
typedef __attribute__((ext_vector_type(4))) float floatx4;

#define LN_EPS 1e-5f

__device__ __forceinline__ float b2f(u16 u) {
    return __builtin_bit_cast(float, (u32)u << 16);
}
__device__ __forceinline__ u16 f2b(float f) {
    u32 x = __builtin_bit_cast(u32, f);
    return (u16)((x + 0x7fffu + ((x >> 16) & 1u)) >> 16);
}

// ---------------------------------------------------------------------------
// GEMM: C = A[M,K] @ BT[Nb,K]^T (+bias f32) with templated scatter epilogues.
// A is f32 (AF32=1, converted to bf16 during LDS staging) or bf16 (AF32=0).
// B (weights/probs/V) always bf16. Block 256 = 4 waves; tile 128x128; wave
// 64x64 (4x4 MFMA 16x16x32 bf16). LDS stride 40 elems: conflict-free.
// K mult of 32; M mult of 128; Nb arbitrary (B rows clamped, epilogue checked).
// Epilogues:
//  0 TOK   : C[z*sC + m*Nb+n] bf16                        [FFN]
//  1 F32   : C[z*sC + m*Nb+n] f32                         [scores]
//  2 QK    : C[(n/12)*393216 + (m&511)*768 + (m>>9)*12 + n%12]   [row Q,K]
//  3 VT    : C[(n/12)*393216 + ((m>>9)*12 + n%12)*512 + (m&511)] [row V^T]
//  4 ROWOUT: C[((n/12)*512 + m)*768 + colbase + z*12 + n%12]     [row PV out]
//  5 COLQKV: C[(n/12)*393216 + (m&511)*768 + (m>>9)*12 + n%12]   [col q,k,v]
// ---------------------------------------------------------------------------
#define BM 128
#define BN 128
#define BK 32
#define LDSP 40

template<int EPI, int RELU, int HASBIAS, int AF32>
__global__ __launch_bounds__(256, 2) void gemm_bt_kernel(
    const void* __restrict__ A, const u16* __restrict__ BT,
    const float* __restrict__ bias, void* __restrict__ C,
    int M, int Nb, int K, long sA, long sB, long sC, int colbase)
{
    __shared__ __align__(16) u16 As[BM * LDSP];
    __shared__ __align__(16) u16 Bs[BN * LDSP];

    const u16* Bb = BT + (long)blockIdx.z * sB;
    const int m0 = blockIdx.y * BM;
    const int n0 = blockIdx.x * BN;
    const int tid = threadIdx.x;
    const int lane = tid & 63;
    const int wm = ((tid >> 6) >> 1) * 64;
    const int wn = ((tid >> 6) & 1) * 64;
    const int lrow = lane & 15;
    const int quad = lane >> 4;

    floatx4 acc[4][4];
#pragma unroll
    for (int i = 0; i < 4; i++)
#pragma unroll
        for (int j = 0; j < 4; j++)
            acc[i][j] = (floatx4){0.f, 0.f, 0.f, 0.f};

    for (int kt = 0; kt < K; kt += BK) {
#pragma unroll
        for (int it = 0; it < 2; it++) {
            int idx = tid + it * 256;       // 0..511
            int row = idx >> 2;             // 0..127
            int ch  = (idx & 3) * 8;        // 0,8,16,24
            int rb = n0 + row; if (rb > Nb - 1) rb = Nb - 1;  // clamp B rows
            if (AF32) {
                const float* Ab = (const float*)A + (long)blockIdx.z * sA;
                const float* src = &Ab[(long)(m0 + row) * K + kt + ch];
                float4 f0 = *(const float4*)(src);
                float4 f1 = *(const float4*)(src + 4);
                u16 t8[8] = { f2b(f0.x), f2b(f0.y), f2b(f0.z), f2b(f0.w),
                              f2b(f1.x), f2b(f1.y), f2b(f1.z), f2b(f1.w) };
                *(uint4*)&As[row * LDSP + ch] = *(const uint4*)t8;
            } else {
                const u16* Ab = (const u16*)A + (long)blockIdx.z * sA;
                *(uint4*)&As[row * LDSP + ch] =
                    *(const uint4*)&Ab[(long)(m0 + row) * K + kt + ch];
            }
            *(uint4*)&Bs[row * LDSP + ch] =
                *(const uint4*)&Bb[(long)rb * K + kt + ch];
        }
        __syncthreads();

        short8 af[4], bfr[4];
#pragma unroll
        for (int i = 0; i < 4; i++)
            af[i] = *(const short8*)&As[(wm + i * 16 + lrow) * LDSP + quad * 8];
#pragma unroll
        for (int j = 0; j < 4; j++)
            bfr[j] = *(const short8*)&Bs[(wn + j * 16 + lrow) * LDSP + quad * 8];
#pragma unroll
        for (int i = 0; i < 4; i++)
#pragma unroll
            for (int j = 0; j < 4; j++)
                acc[i][j] = __builtin_amdgcn_mfma_f32_16x16x32_bf16(
                    af[i], bfr[j], acc[i][j], 0, 0, 0);
        __syncthreads();
    }

    // D element (row = quad*4+r, col = lane&15) — verified layout (m89/m91)
    const int z = blockIdx.z;
#pragma unroll
    for (int j = 0; j < 4; j++) {
        const int n = n0 + wn + j * 16 + lrow;
        if (n >= Nb) continue;
        const float bv = HASBIAS ? bias[colbase + n] : 0.0f;
        const int hh = n / 12;
        const int cc = n - hh * 12;
#pragma unroll
        for (int i = 0; i < 4; i++) {
            const int mbase = m0 + wm + i * 16 + quad * 4;
#pragma unroll
            for (int r = 0; r < 4; r++) {
                const int m = mbase + r;
                float v = acc[i][j][r] + bv;
                if (RELU) v = fmaxf(v, 0.0f);
                if (EPI == 0) {
                    ((u16*)C)[(long)z * sC + (long)m * Nb + n] = f2b(v);
                } else if (EPI == 1) {
                    ((float*)C)[(long)z * sC + (long)m * Nb + n] = v;
                } else if (EPI == 2) {
                    const int s = m >> 9, iL = m & 511;
                    ((u16*)C)[(long)hh * 393216 + (long)iL * 768 + s * 12 + cc] = f2b(v);
                } else if (EPI == 3) {
                    const int s = m >> 9, iL = m & 511;
                    ((u16*)C)[(long)hh * 393216 + (long)(s * 12 + cc) * 512 + iL] = f2b(v);
                } else if (EPI == 4) {
                    ((u16*)C)[((long)hh * 512 + m) * 768 + colbase + z * 12 + cc] = f2b(v);
                } else if (EPI == 5) {
                    const int s = m >> 9, l = m & 511;
                    ((u16*)C)[(long)hh * 393216 + (long)l * 768 + s * 12 + cc] = f2b(v);
                }
            }
        }
    }
}

// ---------------------------------------------------------------------------
// 32x32 tiled transpose + cast: Out[c][r] = bf16(In[r][c]); Out ld = R
// ---------------------------------------------------------------------------
__global__ __launch_bounds__(256) void transpose_kernel(
    const float* __restrict__ In, u16* __restrict__ Out, int R, int Ccols)
{
    __shared__ u16 tile[32][33];
    int tx = threadIdx.x & 31;
    int ty = threadIdx.x >> 5;
    int c0 = blockIdx.x * 32;
    int r0 = blockIdx.y * 32;
#pragma unroll
    for (int rr = 0; rr < 32; rr += 8)
        tile[ty + rr][tx] = f2b(In[(long)(r0 + ty + rr) * Ccols + c0 + tx]);
    __syncthreads();
#pragma unroll
    for (int rr = 0; rr < 32; rr += 8)
        Out[(long)(c0 + ty + rr) * R + r0 + tx] = tile[tx][ty + rr];
}

// ---------------------------------------------------------------------------
// Row softmax over 512 (f32 scores -> bf16 probs); one 256-block per row
// ---------------------------------------------------------------------------
__global__ __launch_bounds__(256) void softmax_kernel(
    const float* __restrict__ S, u16* __restrict__ P)
{
    const long r = blockIdx.x;
    const float* sp = S + r * 512;
    int t = threadIdx.x;
    float a = sp[t], b = sp[t + 256];
    __shared__ float red[256];
    red[t] = fmaxf(a, b);
    __syncthreads();
    for (int o = 128; o > 0; o >>= 1) {
        if (t < o) red[t] = fmaxf(red[t], red[t + o]);
        __syncthreads();
    }
    float mx = red[0];
    __syncthreads();
    float ea = __expf(a - mx), eb = __expf(b - mx);
    red[t] = ea + eb;
    __syncthreads();
    for (int o = 128; o > 0; o >>= 1) {
        if (t < o) red[t] += red[t + o];
        __syncthreads();
    }
    float inv = 1.0f / red[0];
    P[r * 512 + t] = f2b(ea * inv);
    P[r * 512 + t + 256] = f2b(eb * inv);
}

// ---------------------------------------------------------------------------
// out = LN(Xa + Xb) * g + be ; Xa dtype AF (1=f32), Xb dtype BF, out OF
// ---------------------------------------------------------------------------
template<int AF, int BF, int OF>
__global__ __launch_bounds__(256) void ln_add_kernel(
    const void* __restrict__ Xa, const void* __restrict__ Xb,
    const float* __restrict__ g, const float* __restrict__ be,
    void* __restrict__ Out)
{
    const long r = blockIdx.x;
    int t = threadIdx.x;
    float v[3]; float sm = 0.f, s2 = 0.f;
#pragma unroll
    for (int e = 0; e < 3; e++) {
        long c = r * 768 + t + e * 256;
        float xa = AF ? ((const float*)Xa)[c] : b2f(((const u16*)Xa)[c]);
        float xb = BF ? ((const float*)Xb)[c] : b2f(((const u16*)Xb)[c]);
        float x = xa + xb;
        v[e] = x; sm += x; s2 += x * x;
    }
    __shared__ float r1[256], r2[256];
    r1[t] = sm; r2[t] = s2;
    __syncthreads();
    for (int o = 128; o > 0; o >>= 1) {
        if (t < o) { r1[t] += r1[t + o]; r2[t] += r2[t + o]; }
        __syncthreads();
    }
    float mean = r1[0] * (1.0f / 768.0f);
    float var  = r2[0] * (1.0f / 768.0f) - mean * mean;
    float rstd = rsqrtf(var + LN_EPS);
#pragma unroll
    for (int e = 0; e < 3; e++) {
        int c = t + e * 256;
        float o = (v[e] - mean) * rstd * g[c] + be[c];
        if (OF) ((float*)Out)[r * 768 + c] = o;
        else    ((u16*)Out)[r * 768 + c] = f2b(o);
    }
}

// ---------------------------------------------------------------------------
// Fused double-LN: Out(f32) = LN2( X + LN1(A + B) ); A,B bf16, X f32
// ---------------------------------------------------------------------------
__global__ __launch_bounds__(256) void ln_ln_kernel(
    const u16* __restrict__ A, const u16* __restrict__ B,
    const float* __restrict__ X,
    const float* __restrict__ g1, const float* __restrict__ be1,
    const float* __restrict__ g2, const float* __restrict__ be2,
    float* __restrict__ Out)
{
    const long r = blockIdx.x;
    int t = threadIdx.x;
    __shared__ float r1[256], r2[256];

    float u[3]; float sm = 0.f, s2 = 0.f;
#pragma unroll
    for (int e = 0; e < 3; e++) {
        long c = r * 768 + t + e * 256;
        float x = b2f(A[c]) + b2f(B[c]);
        u[e] = x; sm += x; s2 += x * x;
    }
    r1[t] = sm; r2[t] = s2;
    __syncthreads();
    for (int o = 128; o > 0; o >>= 1) {
        if (t < o) { r1[t] += r1[t + o]; r2[t] += r2[t + o]; }
        __syncthreads();
    }
    float mean1 = r1[0] * (1.0f / 768.0f);
    float var1  = r2[0] * (1.0f / 768.0f) - mean1 * mean1;
    float rstd1 = rsqrtf(var1 + LN_EPS);
    __syncthreads();

    float w[3]; sm = 0.f; s2 = 0.f;
#pragma unroll
    for (int e = 0; e < 3; e++) {
        int c = t + e * 256;
        float tv = (u[e] - mean1) * rstd1 * g1[c] + be1[c];
        float wv = X[r * 768 + c] + tv;
        w[e] = wv; sm += wv; s2 += wv * wv;
    }
    r1[t] = sm; r2[t] = s2;
    __syncthreads();
    for (int o = 128; o > 0; o >>= 1) {
        if (t < o) { r1[t] += r1[t + o]; r2[t] += r2[t + o]; }
        __syncthreads();
    }
    float mean2 = r1[0] * (1.0f / 768.0f);
    float var2  = r2[0] * (1.0f / 768.0f) - mean2 * mean2;
    float rstd2 = rsqrtf(var2 + LN_EPS);
#pragma unroll
    for (int e = 0; e < 3; e++) {
        int c = t + e * 256;
        Out[r * 768 + c] = (w[e] - mean2) * rstd2 * g2[c] + be2[c];
    }
}

// ---------------------------------------------------------------------------
// Col attention for one 16-head group. Slices qc/kc/vc: [h'][l][s*12+c].
// Block = (h', l), 64 threads; thread i = query S-row.
// ---------------------------------------------------------------------------
__global__ __launch_bounds__(64) void col_attn_kernel(
    const u16* __restrict__ qc, const u16* __restrict__ kc,
    const u16* __restrict__ vc, u16* __restrict__ Out, int hbase)
{
    const int hh = blockIdx.x >> 9;
    const int l  = blockIdx.x & 511;
    const int i  = threadIdx.x;
    const long base = ((long)hh * 512 + l) * 768;
    __shared__ float Ks[64][12];
    __shared__ float Vs[64][12];
    float q[12];
#pragma unroll
    for (int c = 0; c < 12; c++) {
        q[c] = b2f(qc[base + i * 12 + c]);
        Ks[i][c] = b2f(kc[base + i * 12 + c]);
        Vs[i][c] = b2f(vc[base + i * 12 + c]);
    }
    __syncthreads();
    float sc[64];
#pragma unroll
    for (int j = 0; j < 64; j++) {
        float a = 0.f;
#pragma unroll
        for (int c = 0; c < 12; c++) a += q[c] * Ks[j][c];
        sc[j] = a;
    }
    float m = sc[0];
#pragma unroll
    for (int j = 1; j < 64; j++) m = fmaxf(m, sc[j]);
    float sum = 0.f;
#pragma unroll
    for (int j = 0; j < 64; j++) { sc[j] = __expf(sc[j] - m); sum += sc[j]; }
    float inv = 1.0f / sum;
    float o[12];
#pragma unroll
    for (int c = 0; c < 12; c++) o[c] = 0.f;
#pragma unroll
    for (int j = 0; j < 64; j++) {
        float p = sc[j] * inv;
#pragma unroll
        for (int c = 0; c < 12; c++) o[c] += p * Vs[j][c];
    }
    u16* op = Out + ((long)i * 512 + l) * 768 + hbase + hh * 12;
#pragma unroll
    for (int c = 0; c < 12; c++) op[c] = f2b(o[c]);
}

// ---------------------------------------------------------------------------
extern "C" void kernel_launch(void* const* d_in, const int* in_sizes, int n_in,
                              void* d_out, int out_size, void* d_ws, size_t ws_size,
                              hipStream_t stream)
{
    (void)in_sizes; (void)n_in; (void)out_size; (void)ws_size;

    const float* x     = (const float*)d_in[0];
    const float* w_row = (const float*)d_in[1];
    const float* b_row = (const float*)d_in[2];
    const float* w_col = (const float*)d_in[3];
    const float* b_col = (const float*)d_in[4];
    const float* g_a1  = (const float*)d_in[5];
    const float* be_a1 = (const float*)d_in[6];
    const float* g_a2  = (const float*)d_in[7];
    const float* be_a2 = (const float*)d_in[8];
    const float* w1    = (const float*)d_in[9];
    const float* b1f   = (const float*)d_in[10];
    const float* w2    = (const float*)d_in[11];
    const float* b2f_  = (const float*)d_in[12];
    const float* g_n1  = (const float*)d_in[13];
    const float* be_n1 = (const float*)d_in[14];
    const float* g_n2  = (const float*)d_in[15];
    const float* be_n2 = (const float*)d_in[16];
    float* outp = (float*)d_out;

    // ---- workspace layout (~172 MiB; all sizes multiple of 256 B) ----
    char* wp = (char*)d_ws;
    auto alloc = [&](size_t bytes) -> void* {
        void* p = (void*)wp;
        wp += (bytes + 255) & ~(size_t)255;
        return p;
    };
    u16*   wTrow  = (u16*)alloc((size_t)2304 * 768 * 2);        // 3.4 MiB
    u16*   wTcol  = (u16*)alloc((size_t)2304 * 768 * 2);        // 3.4 MiB
    u16*   w1T    = (u16*)alloc((size_t)3072 * 768 * 2);        // 4.5 MiB
    u16*   w2T    = (u16*)alloc((size_t)768 * 3072 * 2);        // 4.5 MiB
    u16*   bufA   = (u16*)alloc((size_t)32768 * 768 * 2);       // 48 MiB: rowout/colout/ffb
    u16*   bufB   = (u16*)alloc((size_t)32768 * 768 * 2);       // 48 MiB: out1
    u16*   Qg     = (u16*)alloc((size_t)16 * 512 * 768 * 2);    // 12 MiB  } slices; later
    u16*   Kg     = (u16*)alloc((size_t)16 * 512 * 768 * 2);    // 12 MiB  } FFN hidden
    u16*   Vg     = (u16*)alloc((size_t)16 * 512 * 768 * 2);    // 12 MiB  } (contiguous
    float* scores = (float*)alloc((size_t)16 * 512 * 512 * 4);  // 16 MiB  }  60 MiB)
    u16*   probs  = (u16*)alloc((size_t)16 * 512 * 512 * 2);    // 8 MiB   }
    u16*   hidden = Qg;      // alias: slices+scores dead during FFN (48 MiB)
    float* y      = outp;    // y (f32) lives in d_out until final in-place LN

    // ---- weight transposes (f32 -> bf16, BT layout) ----
    transpose_kernel<<<dim3(72, 24), 256, 0, stream>>>(w_row, wTrow, 768, 2304);
    transpose_kernel<<<dim3(72, 24), 256, 0, stream>>>(w_col, wTcol, 768, 2304);
    transpose_kernel<<<dim3(96, 24), 256, 0, stream>>>(w1,   w1T,   768, 3072);
    transpose_kernel<<<dim3(24, 96), 256, 0, stream>>>(w2,   w2T,   3072, 768);

    // ---- row (tied) attention, 4 groups of 16 heads ----
    for (int hg = 0; hg < 4; hg++) {
        const int cbq = hg * 192, cbk = 768 + hg * 192, cbv = 1536 + hg * 192;
        gemm_bt_kernel<2, 0, 1, 1><<<dim3(2, 256), 256, 0, stream>>>(
            x, wTrow + (long)cbq * 768, b_row, Qg, 32768, 192, 768, 0, 0, 0, cbq);
        gemm_bt_kernel<2, 0, 1, 1><<<dim3(2, 256), 256, 0, stream>>>(
            x, wTrow + (long)cbk * 768, b_row, Kg, 32768, 192, 768, 0, 0, 0, cbk);
        gemm_bt_kernel<3, 0, 1, 1><<<dim3(2, 256), 256, 0, stream>>>(
            x, wTrow + (long)cbv * 768, b_row, Vg, 32768, 192, 768, 0, 0, 0, cbv);
        gemm_bt_kernel<1, 0, 0, 0><<<dim3(4, 4, 16), 256, 0, stream>>>(
            Qg, Kg, nullptr, scores, 512, 512, 768,
            (long)512 * 768, (long)512 * 768, (long)512 * 512, 0);
        softmax_kernel<<<8192, 256, 0, stream>>>(scores, probs);
        gemm_bt_kernel<4, 0, 0, 0><<<dim3(6, 4, 16), 256, 0, stream>>>(
            probs, Vg, nullptr, bufA, 512, 768, 512,
            (long)512 * 512, (long)768 * 512, 0, hg * 192);
    }
    // out1 = LN(x + rowout)
    ln_add_kernel<1, 0, 0><<<32768, 256, 0, stream>>>(x, bufA, g_a1, be_a1, bufB);

    // ---- col attention, 4 groups of 16 heads ----
    for (int hg = 0; hg < 4; hg++) {
        const int cbq = hg * 192, cbk = 768 + hg * 192, cbv = 1536 + hg * 192;
        gemm_bt_kernel<5, 0, 1, 0><<<dim3(2, 256), 256, 0, stream>>>(
            bufB, wTcol + (long)cbq * 768, b_col, Qg, 32768, 192, 768, 0, 0, 0, cbq);
        gemm_bt_kernel<5, 0, 1, 0><<<dim3(2, 256), 256, 0, stream>>>(
            bufB, wTcol + (long)cbk * 768, b_col, Kg, 32768, 192, 768, 0, 0, 0, cbk);
        gemm_bt_kernel<5, 0, 1, 0><<<dim3(2, 256), 256, 0, stream>>>(
            bufB, wTcol + (long)cbv * 768, b_col, Vg, 32768, 192, 768, 0, 0, 0, cbv);
        col_attn_kernel<<<8192, 64, 0, stream>>>(Qg, Kg, Vg, bufA, hg * 192);
    }
    // y = LN(x + LN(out1 + colout))  -> d_out (f32 scratch)
    ln_ln_kernel<<<32768, 256, 0, stream>>>(
        bufB, bufA, x, g_a2, be_a2, g_n1, be_n1, y);

    // ---- FFN, 4 chunks of 8192 rows (hidden overlays slices region) ----
    for (int mc = 0; mc < 4; mc++) {
        const long off = (long)mc * 8192 * 768;
        gemm_bt_kernel<0, 1, 1, 1><<<dim3(24, 64), 256, 0, stream>>>(
            y + off, w1T, b1f, hidden, 8192, 3072, 768, 0, 0, 0, 0);
        gemm_bt_kernel<0, 0, 1, 0><<<dim3(6, 64), 256, 0, stream>>>(
            hidden, w2T, b2f_, bufA + off, 8192, 768, 3072, 0, 0, 0, 0);
    }
    // final: out = LN(y + ffb), in-place over d_out (per-row, block-local)
    ln_add_kernel<1, 0, 1><<<32768, 256, 0, stream>>>(y, bufA, g_n2, be_n2, outp);
}

// Round 4
// 2121.457 us; speedup vs baseline: 1.0178x; 1.0178x over previous
//
#include <hip/hip_runtime.h>

typedef unsigned short u16;
typedef unsigned int u32;
typedef __attribute__((ext_vector_type(8))) short short8;
typedef __attribute__((ext_vector_type(4))) float floatx4;

#define LN_EPS 1e-5f
#define REG 6291456L   // 16*512*768: Q->K->V region stride in qkvg

__device__ __forceinline__ float b2f(u16 u) {
    return __builtin_bit_cast(float, (u32)u << 16);
}
__device__ __forceinline__ u16 f2b(float f) {
    u32 x = __builtin_bit_cast(u32, f);
    return (u16)((x + 0x7fffu + ((x >> 16) & 1u)) >> 16);
}

// ---------------------------------------------------------------------------
// GEMM: C = A[M,K] @ BT[Nb,K]^T (+bias f32) with templated scatter epilogues.
// A is f32 (AF32=1, converted to bf16 during LDS staging) or bf16 (AF32=0).
// Block 256 = 4 waves; tile 128x128; wave 64x64 (4x4 MFMA 16x16x32 bf16).
// LDS stride 40 elems: conflict-free. K mult 32; M mult 128; Nb arbitrary.
// Epilogues:
//  0 TOK   : C[m*Nb+n] bf16                                [FFN]
//  1 F32   : C[z*sC + m*Nb+n] f32                          [scores]
//  4 ROWOUT: C[((n/12)*512 + m)*768 + colbase + z*12 + n%12]   [row PV out]
//  6 QKVROW: fused q/k/v scatter, t=n/192: Q,K head-major; V transposed
//  7 QKVCOL: fused q/k/v scatter, all token-layout [h'][l][s*12+c]
// For 6/7: C = qkvg base; bias idx = t*768 + colbase + (n%192).
// ---------------------------------------------------------------------------
#define BM 128
#define BN 128
#define BK 32
#define LDSP 40

template<int EPI, int RELU, int HASBIAS, int AF32>
__global__ __launch_bounds__(256, 2) void gemm_bt_kernel(
    const void* __restrict__ A, const u16* __restrict__ BT,
    const float* __restrict__ bias, void* __restrict__ C,
    int M, int Nb, int K, long sA, long sB, long sC, int colbase)
{
    __shared__ __align__(16) u16 As[BM * LDSP];
    __shared__ __align__(16) u16 Bs[BN * LDSP];

    const u16* Bb = BT + (long)blockIdx.z * sB;
    const int m0 = blockIdx.y * BM;
    const int n0 = blockIdx.x * BN;
    const int tid = threadIdx.x;
    const int lane = tid & 63;
    const int wm = ((tid >> 6) >> 1) * 64;
    const int wn = ((tid >> 6) & 1) * 64;
    const int lrow = lane & 15;
    const int quad = lane >> 4;

    floatx4 acc[4][4];
#pragma unroll
    for (int i = 0; i < 4; i++)
#pragma unroll
        for (int j = 0; j < 4; j++)
            acc[i][j] = (floatx4){0.f, 0.f, 0.f, 0.f};

    for (int kt = 0; kt < K; kt += BK) {
#pragma unroll
        for (int it = 0; it < 2; it++) {
            int idx = tid + it * 256;       // 0..511
            int row = idx >> 2;             // 0..127
            int ch  = (idx & 3) * 8;        // 0,8,16,24
            int rb = n0 + row; if (rb > Nb - 1) rb = Nb - 1;  // clamp B rows
            if (AF32) {
                const float* Ab = (const float*)A + (long)blockIdx.z * sA;
                const float* src = &Ab[(long)(m0 + row) * K + kt + ch];
                float4 f0 = *(const float4*)(src);
                float4 f1 = *(const float4*)(src + 4);
                u16 t8[8] = { f2b(f0.x), f2b(f0.y), f2b(f0.z), f2b(f0.w),
                              f2b(f1.x), f2b(f1.y), f2b(f1.z), f2b(f1.w) };
                *(uint4*)&As[row * LDSP + ch] = *(const uint4*)t8;
            } else {
                const u16* Ab = (const u16*)A + (long)blockIdx.z * sA;
                *(uint4*)&As[row * LDSP + ch] =
                    *(const uint4*)&Ab[(long)(m0 + row) * K + kt + ch];
            }
            *(uint4*)&Bs[row * LDSP + ch] =
                *(const uint4*)&Bb[(long)rb * K + kt + ch];
        }
        __syncthreads();

        short8 af[4], bfr[4];
#pragma unroll
        for (int i = 0; i < 4; i++)
            af[i] = *(const short8*)&As[(wm + i * 16 + lrow) * LDSP + quad * 8];
#pragma unroll
        for (int j = 0; j < 4; j++)
            bfr[j] = *(const short8*)&Bs[(wn + j * 16 + lrow) * LDSP + quad * 8];
#pragma unroll
        for (int i = 0; i < 4; i++)
#pragma unroll
            for (int j = 0; j < 4; j++)
                acc[i][j] = __builtin_amdgcn_mfma_f32_16x16x32_bf16(
                    af[i], bfr[j], acc[i][j], 0, 0, 0);
        __syncthreads();
    }

    // D element (row = quad*4+r, col = lane&15) — verified layout (m89/m91)
    const int z = blockIdx.z;
#pragma unroll
    for (int j = 0; j < 4; j++) {
        const int n = n0 + wn + j * 16 + lrow;
        if (n >= Nb) continue;
        float bv = 0.0f;
        int t = 0, jj = 0, hl = 0, cc = 0;
        if (EPI == 6 || EPI == 7) {
            t = n / 192; jj = n - t * 192;
            hl = jj / 12; cc = jj - hl * 12;
            if (HASBIAS) bv = bias[t * 768 + colbase + jj];
        } else {
            hl = n / 12; cc = n - hl * 12;
            if (HASBIAS) bv = bias[colbase + n];
        }
#pragma unroll
        for (int i = 0; i < 4; i++) {
            const int mbase = m0 + wm + i * 16 + quad * 4;
#pragma unroll
            for (int r = 0; r < 4; r++) {
                const int m = mbase + r;
                float v = acc[i][j][r] + bv;
                if (RELU) v = fmaxf(v, 0.0f);
                if (EPI == 0) {
                    ((u16*)C)[(long)z * sC + (long)m * Nb + n] = f2b(v);
                } else if (EPI == 1) {
                    ((float*)C)[(long)z * sC + (long)m * Nb + n] = v;
                } else if (EPI == 4) {
                    ((u16*)C)[((long)hl * 512 + m) * 768 + colbase + z * 12 + cc] = f2b(v);
                } else if (EPI == 6) {
                    const int s = m >> 9, iL = m & 511;
                    if (t < 2)
                        ((u16*)C)[t * REG + ((long)hl * 512 + iL) * 768 + s * 12 + cc] = f2b(v);
                    else
                        ((u16*)C)[2 * REG + (long)hl * 393216 + (long)(s * 12 + cc) * 512 + iL] = f2b(v);
                } else if (EPI == 7) {
                    const int s = m >> 9, l = m & 511;
                    ((u16*)C)[(long)t * REG + (long)hl * 393216 + (long)l * 768 + s * 12 + cc] = f2b(v);
                }
            }
        }
    }
}

// ---------------------------------------------------------------------------
// 32x32 tiled transpose + cast: Out[c][r] = bf16(In[r][c]); Out ld = R
// ---------------------------------------------------------------------------
__global__ __launch_bounds__(256) void transpose_kernel(
    const float* __restrict__ In, u16* __restrict__ Out, int R, int Ccols)
{
    __shared__ u16 tile[32][33];
    int tx = threadIdx.x & 31;
    int ty = threadIdx.x >> 5;
    int c0 = blockIdx.x * 32;
    int r0 = blockIdx.y * 32;
#pragma unroll
    for (int rr = 0; rr < 32; rr += 8)
        tile[ty + rr][tx] = f2b(In[(long)(r0 + ty + rr) * Ccols + c0 + tx]);
    __syncthreads();
#pragma unroll
    for (int rr = 0; rr < 32; rr += 8)
        Out[(long)(c0 + ty + rr) * R + r0 + tx] = tile[tx][ty + rr];
}

// ---------------------------------------------------------------------------
// Pack W[768][2304] -> wPack[2304][768] bf16 with grouped-QKV row order:
// packed row p: hg=p/576, r=p%576, t=r/192, j=r%192 -> src col t*768+hg*192+j.
// 192 and 576 are multiples of 32 so 32-wide tiles never straddle segments.
// ---------------------------------------------------------------------------
__global__ __launch_bounds__(256) void qkv_pack_kernel(
    const float* __restrict__ In, u16* __restrict__ Out)
{
    __shared__ u16 tile[32][33];
    int tx = threadIdx.x & 31;
    int ty = threadIdx.x >> 5;
    int p0 = blockIdx.x * 32;
    int k0 = blockIdx.y * 32;
    int hg = p0 / 576, r0 = p0 % 576;
    int t = r0 / 192, j0 = r0 % 192;
    int c0 = t * 768 + hg * 192 + j0;
#pragma unroll
    for (int rr = 0; rr < 32; rr += 8)
        tile[ty + rr][tx] = f2b(In[(long)(k0 + ty + rr) * 2304 + c0 + tx]);
    __syncthreads();
#pragma unroll
    for (int rr = 0; rr < 32; rr += 8)
        Out[(long)(p0 + ty + rr) * 768 + k0 + tx] = tile[tx][ty + rr];
}

// ---------------------------------------------------------------------------
// Row softmax over 512 (f32 scores -> bf16 probs); one 256-block per row
// ---------------------------------------------------------------------------
__global__ __launch_bounds__(256) void softmax_kernel(
    const float* __restrict__ S, u16* __restrict__ P)
{
    const long r = blockIdx.x;
    const float* sp = S + r * 512;
    int t = threadIdx.x;
    float a = sp[t], b = sp[t + 256];
    __shared__ float red[256];
    red[t] = fmaxf(a, b);
    __syncthreads();
    for (int o = 128; o > 0; o >>= 1) {
        if (t < o) red[t] = fmaxf(red[t], red[t + o]);
        __syncthreads();
    }
    float mx = red[0];
    __syncthreads();
    float ea = __expf(a - mx), eb = __expf(b - mx);
    red[t] = ea + eb;
    __syncthreads();
    for (int o = 128; o > 0; o >>= 1) {
        if (t < o) red[t] += red[t + o];
        __syncthreads();
    }
    float inv = 1.0f / red[0];
    P[r * 512 + t] = f2b(ea * inv);
    P[r * 512 + t + 256] = f2b(eb * inv);
}

// ---------------------------------------------------------------------------
// out = LN(Xa + Xb) * g + be ; Xa dtype AF (1=f32), Xb dtype BF, out OF
// ---------------------------------------------------------------------------
template<int AF, int BF, int OF>
__global__ __launch_bounds__(256) void ln_add_kernel(
    const void* __restrict__ Xa, const void* __restrict__ Xb,
    const float* __restrict__ g, const float* __restrict__ be,
    void* __restrict__ Out)
{
    const long r = blockIdx.x;
    int t = threadIdx.x;
    float v[3]; float sm = 0.f, s2 = 0.f;
#pragma unroll
    for (int e = 0; e < 3; e++) {
        long c = r * 768 + t + e * 256;
        float xa = AF ? ((const float*)Xa)[c] : b2f(((const u16*)Xa)[c]);
        float xb = BF ? ((const float*)Xb)[c] : b2f(((const u16*)Xb)[c]);
        float x = xa + xb;
        v[e] = x; sm += x; s2 += x * x;
    }
    __shared__ float r1[256], r2[256];
    r1[t] = sm; r2[t] = s2;
    __syncthreads();
    for (int o = 128; o > 0; o >>= 1) {
        if (t < o) { r1[t] += r1[t + o]; r2[t] += r2[t + o]; }
        __syncthreads();
    }
    float mean = r1[0] * (1.0f / 768.0f);
    float var  = r2[0] * (1.0f / 768.0f) - mean * mean;
    float rstd = rsqrtf(var + LN_EPS);
#pragma unroll
    for (int e = 0; e < 3; e++) {
        int c = t + e * 256;
        float o = (v[e] - mean) * rstd * g[c] + be[c];
        if (OF) ((float*)Out)[r * 768 + c] = o;
        else    ((u16*)Out)[r * 768 + c] = f2b(o);
    }
}

// ---------------------------------------------------------------------------
// Fused double-LN: Out(f32) = LN2( X + LN1(A + B) ); A,B bf16, X f32
// ---------------------------------------------------------------------------
__global__ __launch_bounds__(256) void ln_ln_kernel(
    const u16* __restrict__ A, const u16* __restrict__ B,
    const float* __restrict__ X,
    const float* __restrict__ g1, const float* __restrict__ be1,
    const float* __restrict__ g2, const float* __restrict__ be2,
    float* __restrict__ Out)
{
    const long r = blockIdx.x;
    int t = threadIdx.x;
    __shared__ float r1[256], r2[256];

    float u[3]; float sm = 0.f, s2 = 0.f;
#pragma unroll
    for (int e = 0; e < 3; e++) {
        long c = r * 768 + t + e * 256;
        float x = b2f(A[c]) + b2f(B[c]);
        u[e] = x; sm += x; s2 += x * x;
    }
    r1[t] = sm; r2[t] = s2;
    __syncthreads();
    for (int o = 128; o > 0; o >>= 1) {
        if (t < o) { r1[t] += r1[t + o]; r2[t] += r2[t + o]; }
        __syncthreads();
    }
    float mean1 = r1[0] * (1.0f / 768.0f);
    float var1  = r2[0] * (1.0f / 768.0f) - mean1 * mean1;
    float rstd1 = rsqrtf(var1 + LN_EPS);
    __syncthreads();

    float w[3]; sm = 0.f; s2 = 0.f;
#pragma unroll
    for (int e = 0; e < 3; e++) {
        int c = t + e * 256;
        float tv = (u[e] - mean1) * rstd1 * g1[c] + be1[c];
        float wv = X[r * 768 + c] + tv;
        w[e] = wv; sm += wv; s2 += wv * wv;
    }
    r1[t] = sm; r2[t] = s2;
    __syncthreads();
    for (int o = 128; o > 0; o >>= 1) {
        if (t < o) { r1[t] += r1[t + o]; r2[t] += r2[t + o]; }
        __syncthreads();
    }
    float mean2 = r1[0] * (1.0f / 768.0f);
    float var2  = r2[0] * (1.0f / 768.0f) - mean2 * mean2;
    float rstd2 = rsqrtf(var2 + LN_EPS);
#pragma unroll
    for (int e = 0; e < 3; e++) {
        int c = t + e * 256;
        Out[r * 768 + c] = (w[e] - mean2) * rstd2 * g2[c] + be2[c];
    }
}

// ---------------------------------------------------------------------------
// Col attention for one 16-head group. Slices qc/kc/vc: [h'][l][s*12+c].
// Block = (h', l), 64 threads; thread i = query S-row.
// ---------------------------------------------------------------------------
__global__ __launch_bounds__(64) void col_attn_kernel(
    const u16* __restrict__ qc, const u16* __restrict__ kc,
    const u16* __restrict__ vc, u16* __restrict__ Out, int hbase)
{
    const int hh = blockIdx.x >> 9;
    const int l  = blockIdx.x & 511;
    const int i  = threadIdx.x;
    const long base = ((long)hh * 512 + l) * 768;
    __shared__ float Ks[64][12];
    __shared__ float Vs[64][12];
    float q[12];
#pragma unroll
    for (int c = 0; c < 12; c++) {
        q[c] = b2f(qc[base + i * 12 + c]);
        Ks[i][c] = b2f(kc[base + i * 12 + c]);
        Vs[i][c] = b2f(vc[base + i * 12 + c]);
    }
    __syncthreads();
    float sc[64];
#pragma unroll
    for (int j = 0; j < 64; j++) {
        float a = 0.f;
#pragma unroll
        for (int c = 0; c < 12; c++) a += q[c] * Ks[j][c];
        sc[j] = a;
    }
    float m = sc[0];
#pragma unroll
    for (int j = 1; j < 64; j++) m = fmaxf(m, sc[j]);
    float sum = 0.f;
#pragma unroll
    for (int j = 0; j < 64; j++) { sc[j] = __expf(sc[j] - m); sum += sc[j]; }
    float inv = 1.0f / sum;
    float o[12];
#pragma unroll
    for (int c = 0; c < 12; c++) o[c] = 0.f;
#pragma unroll
    for (int j = 0; j < 64; j++) {
        float p = sc[j] * inv;
#pragma unroll
        for (int c = 0; c < 12; c++) o[c] += p * Vs[j][c];
    }
    u16* op = Out + ((long)i * 512 + l) * 768 + hbase + hh * 12;
#pragma unroll
    for (int c = 0; c < 12; c++) op[c] = f2b(o[c]);
}

// ---------------------------------------------------------------------------
extern "C" void kernel_launch(void* const* d_in, const int* in_sizes, int n_in,
                              void* d_out, int out_size, void* d_ws, size_t ws_size,
                              hipStream_t stream)
{
    (void)in_sizes; (void)n_in; (void)out_size; (void)ws_size;

    const float* x     = (const float*)d_in[0];
    const float* w_row = (const float*)d_in[1];
    const float* b_row = (const float*)d_in[2];
    const float* w_col = (const float*)d_in[3];
    const float* b_col = (const float*)d_in[4];
    const float* g_a1  = (const float*)d_in[5];
    const float* be_a1 = (const float*)d_in[6];
    const float* g_a2  = (const float*)d_in[7];
    const float* be_a2 = (const float*)d_in[8];
    const float* w1    = (const float*)d_in[9];
    const float* b1f   = (const float*)d_in[10];
    const float* w2    = (const float*)d_in[11];
    const float* b2f_  = (const float*)d_in[12];
    const float* g_n1  = (const float*)d_in[13];
    const float* be_n1 = (const float*)d_in[14];
    const float* g_n2  = (const float*)d_in[15];
    const float* be_n2 = (const float*)d_in[16];
    float* outp = (float*)d_out;

    // ---- workspace layout (~172 MiB, same as passing R3 layout) ----
    char* wp = (char*)d_ws;
    auto alloc = [&](size_t bytes) -> void* {
        void* p = (void*)wp;
        wp += (bytes + 255) & ~(size_t)255;
        return p;
    };
    u16*   wProw  = (u16*)alloc((size_t)2304 * 768 * 2);        // 3.4 MiB packed QKV row
    u16*   wPcol  = (u16*)alloc((size_t)2304 * 768 * 2);        // 3.4 MiB packed QKV col
    u16*   w1T    = (u16*)alloc((size_t)3072 * 768 * 2);        // 4.5 MiB
    u16*   w2T    = (u16*)alloc((size_t)768 * 3072 * 2);        // 4.5 MiB
    u16*   bufA   = (u16*)alloc((size_t)32768 * 768 * 2);       // 48 MiB: rowout/colout/ffb
    u16*   bufB   = (u16*)alloc((size_t)32768 * 768 * 2);       // 48 MiB: out1
    u16*   qkvg   = (u16*)alloc((size_t)3 * 16 * 512 * 768 * 2);// 36 MiB: Q|K|V group block
    float* scores = (float*)alloc((size_t)16 * 512 * 512 * 4);  // 16 MiB
    u16*   probs  = (u16*)alloc((size_t)16 * 512 * 512 * 2);    // 8 MiB
    u16*   hidden = qkvg;    // alias: qkvg+scores dead during FFN (48 MiB needed)
    float* y      = outp;    // y (f32) lives in d_out until final in-place LN

    // ---- weight packing/transposes (f32 -> bf16) ----
    qkv_pack_kernel<<<dim3(72, 24), 256, 0, stream>>>(w_row, wProw);
    qkv_pack_kernel<<<dim3(72, 24), 256, 0, stream>>>(w_col, wPcol);
    transpose_kernel<<<dim3(96, 24), 256, 0, stream>>>(w1, w1T, 768, 3072);
    transpose_kernel<<<dim3(24, 96), 256, 0, stream>>>(w2, w2T, 3072, 768);

    // ---- row (tied) attention, 4 groups of 16 heads ----
    for (int hg = 0; hg < 4; hg++) {
        gemm_bt_kernel<6, 0, 1, 1><<<dim3(5, 256), 256, 0, stream>>>(
            x, wProw + (long)hg * 576 * 768, b_row, qkvg,
            32768, 576, 768, 0, 0, 0, hg * 192);
        gemm_bt_kernel<1, 0, 0, 0><<<dim3(4, 4, 16), 256, 0, stream>>>(
            qkvg, qkvg + REG, nullptr, scores, 512, 512, 768,
            (long)512 * 768, (long)512 * 768, (long)512 * 512, 0);
        softmax_kernel<<<8192, 256, 0, stream>>>(scores, probs);
        gemm_bt_kernel<4, 0, 0, 0><<<dim3(6, 4, 16), 256, 0, stream>>>(
            probs, qkvg + 2 * REG, nullptr, bufA, 512, 768, 512,
            (long)512 * 512, (long)768 * 512, 0, hg * 192);
    }
    // out1 = LN(x + rowout)
    ln_add_kernel<1, 0, 0><<<32768, 256, 0, stream>>>(x, bufA, g_a1, be_a1, bufB);

    // ---- col attention, 4 groups of 16 heads ----
    for (int hg = 0; hg < 4; hg++) {
        gemm_bt_kernel<7, 0, 1, 0><<<dim3(5, 256), 256, 0, stream>>>(
            bufB, wPcol + (long)hg * 576 * 768, b_col, qkvg,
            32768, 576, 768, 0, 0, 0, hg * 192);
        col_attn_kernel<<<8192, 64, 0, stream>>>(
            qkvg, qkvg + REG, qkvg + 2 * REG, bufA, hg * 192);
    }
    // y = LN(x + LN(out1 + colout))  -> d_out (f32 scratch)
    ln_ln_kernel<<<32768, 256, 0, stream>>>(
        bufB, bufA, x, g_a2, be_a2, g_n1, be_n1, y);

    // ---- FFN, 4 chunks of 8192 rows (hidden overlays qkvg+scores region) ----
    for (int mc = 0; mc < 4; mc++) {
        const long off = (long)mc * 8192 * 768;
        gemm_bt_kernel<0, 1, 1, 1><<<dim3(24, 64), 256, 0, stream>>>(
            y + off, w1T, b1f, hidden, 8192, 3072, 768, 0, 0, 0, 0);
        gemm_bt_kernel<0, 0, 1, 0><<<dim3(6, 64), 256, 0, stream>>>(
            hidden, w2T, b2f_, bufA + off, 8192, 768, 3072, 0, 0, 0, 0);
    }
    // final: out = LN(y + ffb), in-place over d_out (per-row, block-local)
    ln_add_kernel<1, 0, 1><<<32768, 256, 0, stream>>>(y, bufA, g_n2, be_n2, outp);
}

// Round 5
// 1783.991 us; speedup vs baseline: 1.2104x; 1.1892x over previous
//
#include <hip/hip_runtime.h>

typedef unsigned short u16;
typedef unsigned int u32;
typedef __attribute__((ext_vector_type(8))) short short8;
typedef __attribute__((ext_vector_type(4))) float floatx4;

#define LN_EPS 1e-5f
#define REG 6291456L   // 16*512*768 elems: Q|K|V region stride in qkvg

__device__ __forceinline__ float b2f(u16 u) {
    return __builtin_bit_cast(float, (u32)u << 16);
}
__device__ __forceinline__ u16 f2b(float f) {
    u32 x = __builtin_bit_cast(u32, f);
    return (u16)((x + 0x7fffu + ((x >> 16) & 1u)) >> 16);
}

// async global->LDS, 16B per lane; LDS dest must be base + lane*16 (m97/m104)
__device__ __forceinline__ void gload16(const u16* g, u16* l) {
    __builtin_amdgcn_global_load_lds(
        (const __attribute__((address_space(1))) void*)g,
        (__attribute__((address_space(3))) void*)l, 16, 0, 0);
}

// ---------------------------------------------------------------------------
// Unified MFMA GEMM with global_load_lds staging (unpadded LDS, stride 32).
// C = A[M,K] @ BT[Nb,K]^T (+bias), A/BT bf16. Block 256 = 4 waves (2x2).
// BN_=128: wave 64x64 (4x4 mfma); BN_=192: wave 64x96 (4x6). BK=32.
// M-tile 128. SMAJ=1: block rows = 64 s x 2 i (m = s*2 + i_local, iL0=by*2),
// giving dense full-row writes for head-major/token scatter epilogues.
// Nb must be a multiple of BN_; K a multiple of 32.
// Epilogues:
//  0 TOK   : C[(by*128+ml)*Nb + n] bf16                       [FFN, ld=Nb]
//  1 F32   : C[z*sC + (by*128+ml)*Nb + n] f32                 [scores]
//  3 VT    : C[h*393216 + (s*12+d)*512 + iL]  (s-blocked)     [row V^T]
//  4 ROWOUT: C[(sv*512+m)*768 + colbase + z*12 + d]           [row PV out]
//  8 QKROW : t=n/192 -> C+t*REG, head-major (s-major tiling)  [row Q,K]
//  9 COLQKV: t=n/192 -> C+t*REG, token layout (s-major)       [col q,k,v]
// bias idx: EPI 8/9: t*768+colbase+(n%192); else colbase+n.
// ---------------------------------------------------------------------------
template<int BN_, int EPI, int RELU, int HASBIAS, int SMAJ>
__global__ __launch_bounds__(256, 2) void gemm_dma(
    const u16* __restrict__ A, const u16* __restrict__ BT,
    const float* __restrict__ bias, void* __restrict__ C,
    int Nb, int K, long sA, long sB, long sC, int colbase)
{
    constexpr int NCH = (128 + BN_) / 64;   // 16B DMA chunks per thread
    constexpr int JF  = BN_ / 32;           // B frags per wave
    __shared__ u16 lds[(128 + BN_) * 32];   // A[128][32] then B[BN_][32]

    const u16* Az = A + (long)blockIdx.z * sA;
    const u16* Bz = BT + (long)blockIdx.z * sB;
    const int n0 = blockIdx.x * BN_;
    const int tid = threadIdx.x;
    const int lane = tid & 63;
    const int wm = ((tid >> 6) >> 1) * 64;
    const int wn = ((tid >> 6) & 1) * (BN_ / 2);
    const int lrow = lane & 15;
    const int quad = lane >> 4;

    floatx4 acc[4][JF];
#pragma unroll
    for (int i = 0; i < 4; i++)
#pragma unroll
        for (int j = 0; j < JF; j++)
            acc[i][j] = (floatx4){0.f, 0.f, 0.f, 0.f};

    for (int kt = 0; kt < K; kt += 32) {
#pragma unroll
        for (int it = 0; it < NCH; it++) {
            const int idx = tid + it * 256;
            const u16* src;
            if (idx < 512) {                 // A chunks (wave-uniform branch)
                const int row = idx >> 2;
                const int ch  = (idx & 3) * 8;
                const long grow = SMAJ
                    ? ((long)(row >> 1) * 512 + (blockIdx.y << 1) + (row & 1))
                    : ((long)blockIdx.y * 128 + row);
                src = Az + grow * K + kt + ch;
            } else {                         // B chunks
                const int bidx = idx - 512;
                const int row = bidx >> 2;
                const int ch  = (bidx & 3) * 8;
                src = Bz + (long)(n0 + row) * K + kt + ch;
            }
            gload16(src, &lds[idx * 8]);
        }
        __syncthreads();

        short8 af[4], bfr[JF];
#pragma unroll
        for (int i = 0; i < 4; i++)
            af[i] = *(const short8*)&lds[(wm + i * 16 + lrow) * 32 + quad * 8];
#pragma unroll
        for (int j = 0; j < JF; j++)
            bfr[j] = *(const short8*)&lds[4096 + (wn + j * 16 + lrow) * 32 + quad * 8];
#pragma unroll
        for (int i = 0; i < 4; i++)
#pragma unroll
            for (int j = 0; j < JF; j++)
                acc[i][j] = __builtin_amdgcn_mfma_f32_16x16x32_bf16(
                    af[i], bfr[j], acc[i][j], 0, 0, 0);
        __syncthreads();
    }

    // D element: row = quad*4+r, col = lane&15 (verified m89/m91)
    const int z = blockIdx.z;
#pragma unroll
    for (int j = 0; j < JF; j++) {
        const int n = n0 + wn + j * 16 + lrow;
        int t = 0, jj = n;
        if (EPI == 8 || EPI == 9) { t = n / 192; jj = n - t * 192; }
        const int hl = jj / 12;
        const int cc = jj - hl * 12;
        float bv = 0.f;
        if (HASBIAS)
            bv = (EPI == 8 || EPI == 9) ? bias[t * 768 + colbase + jj]
                                        : bias[colbase + n];
#pragma unroll
        for (int i = 0; i < 4; i++) {
            const int mb = wm + i * 16 + quad * 4;
#pragma unroll
            for (int r = 0; r < 4; r++) {
                const int ml = mb + r;
                float v = acc[i][j][r] + bv;
                if (RELU) v = fmaxf(v, 0.f);
                if (EPI == 0) {
                    const long m = (long)blockIdx.y * 128 + ml;
                    ((u16*)C)[m * Nb + n] = f2b(v);
                } else if (EPI == 1) {
                    const long m = (long)blockIdx.y * 128 + ml;
                    ((float*)C)[(long)z * sC + m * Nb + n] = v;
                } else if (EPI == 3) {
                    const int gm = blockIdx.y * 128 + ml;
                    const int s = gm >> 9, iL = gm & 511;
                    ((u16*)C)[(long)hl * 393216 + (long)(s * 12 + cc) * 512 + iL] = f2b(v);
                } else if (EPI == 4) {
                    const int m = blockIdx.y * 128 + ml;    // hl here = s-value
                    ((u16*)C)[((long)hl * 512 + m) * 768 + colbase + z * 12 + cc] = f2b(v);
                } else if (EPI == 8) {
                    const int s = ml >> 1, iL = (blockIdx.y << 1) + (ml & 1);
                    ((u16*)C)[(long)t * REG + ((long)hl * 512 + iL) * 768 + s * 12 + cc] = f2b(v);
                } else if (EPI == 9) {
                    const int s = ml >> 1, l = (blockIdx.y << 1) + (ml & 1);
                    ((u16*)C)[(long)t * REG + (long)hl * 393216 + (long)l * 768 + s * 12 + cc] = f2b(v);
                }
            }
        }
    }
}

// ---------------------------------------------------------------------------
// x (f32) -> xb (bf16), 8 elems/thread
// ---------------------------------------------------------------------------
__global__ __launch_bounds__(256) void cast_kernel(
    const float* __restrict__ X, u16* __restrict__ Xb)
{
    const long i = ((long)blockIdx.x * 256 + threadIdx.x) * 8;
    float4 a = *(const float4*)(X + i);
    float4 b = *(const float4*)(X + i + 4);
    u16 t8[8] = { f2b(a.x), f2b(a.y), f2b(a.z), f2b(a.w),
                  f2b(b.x), f2b(b.y), f2b(b.z), f2b(b.w) };
    *(uint4*)(Xb + i) = *(const uint4*)t8;
}

// ---------------------------------------------------------------------------
// 32x32 tiled transpose + cast: Out[c][r] = bf16(In[r][c]); Out ld = R
// ---------------------------------------------------------------------------
__global__ __launch_bounds__(256) void transpose_kernel(
    const float* __restrict__ In, u16* __restrict__ Out, int R, int Ccols)
{
    __shared__ u16 tile[32][33];
    int tx = threadIdx.x & 31;
    int ty = threadIdx.x >> 5;
    int c0 = blockIdx.x * 32;
    int r0 = blockIdx.y * 32;
#pragma unroll
    for (int rr = 0; rr < 32; rr += 8)
        tile[ty + rr][tx] = f2b(In[(long)(r0 + ty + rr) * Ccols + c0 + tx]);
    __syncthreads();
#pragma unroll
    for (int rr = 0; rr < 32; rr += 8)
        Out[(long)(c0 + ty + rr) * R + r0 + tx] = tile[tx][ty + rr];
}

// W[768][2304] -> wPqk[1536][768]: row p: hg=p/384, t=(p%384)/192, j=p%192
__global__ __launch_bounds__(256) void pack_qk_kernel(
    const float* __restrict__ In, u16* __restrict__ Out)
{
    __shared__ u16 tile[32][33];
    int tx = threadIdx.x & 31;
    int ty = threadIdx.x >> 5;
    int p0 = blockIdx.x * 32;
    int k0 = blockIdx.y * 32;
    int hg = p0 / 384, rem = p0 % 384;
    int t = rem / 192, j0 = rem % 192;
    int c0 = t * 768 + hg * 192 + j0;
#pragma unroll
    for (int rr = 0; rr < 32; rr += 8)
        tile[ty + rr][tx] = f2b(In[(long)(k0 + ty + rr) * 2304 + c0 + tx]);
    __syncthreads();
#pragma unroll
    for (int rr = 0; rr < 32; rr += 8)
        Out[(long)(p0 + ty + rr) * 768 + k0 + tx] = tile[tx][ty + rr];
}

// W[768][2304] -> wPv[768][768]: row p: hg=p/192, j=p%192 -> col 1536+hg*192+j
__global__ __launch_bounds__(256) void pack_v_kernel(
    const float* __restrict__ In, u16* __restrict__ Out)
{
    __shared__ u16 tile[32][33];
    int tx = threadIdx.x & 31;
    int ty = threadIdx.x >> 5;
    int p0 = blockIdx.x * 32;
    int k0 = blockIdx.y * 32;
    int hg = p0 / 192, j0 = p0 % 192;
    int c0 = 1536 + hg * 192 + j0;
#pragma unroll
    for (int rr = 0; rr < 32; rr += 8)
        tile[ty + rr][tx] = f2b(In[(long)(k0 + ty + rr) * 2304 + c0 + tx]);
    __syncthreads();
#pragma unroll
    for (int rr = 0; rr < 32; rr += 8)
        Out[(long)(p0 + ty + rr) * 768 + k0 + tx] = tile[tx][ty + rr];
}

// W[768][2304] -> wPcol[2304][768]: row p: hg=p/576, t=(p%576)/192, j=p%192
__global__ __launch_bounds__(256) void qkv_pack_kernel(
    const float* __restrict__ In, u16* __restrict__ Out)
{
    __shared__ u16 tile[32][33];
    int tx = threadIdx.x & 31;
    int ty = threadIdx.x >> 5;
    int p0 = blockIdx.x * 32;
    int k0 = blockIdx.y * 32;
    int hg = p0 / 576, r0 = p0 % 576;
    int t = r0 / 192, j0 = r0 % 192;
    int c0 = t * 768 + hg * 192 + j0;
#pragma unroll
    for (int rr = 0; rr < 32; rr += 8)
        tile[ty + rr][tx] = f2b(In[(long)(k0 + ty + rr) * 2304 + c0 + tx]);
    __syncthreads();
#pragma unroll
    for (int rr = 0; rr < 32; rr += 8)
        Out[(long)(p0 + ty + rr) * 768 + k0 + tx] = tile[tx][ty + rr];
}

// ---------------------------------------------------------------------------
// Row softmax over 512 (f32 scores -> bf16 probs); one 256-block per row
// ---------------------------------------------------------------------------
__global__ __launch_bounds__(256) void softmax_kernel(
    const float* __restrict__ S, u16* __restrict__ P)
{
    const long r = blockIdx.x;
    const float* sp = S + r * 512;
    int t = threadIdx.x;
    float a = sp[t], b = sp[t + 256];
    __shared__ float red[256];
    red[t] = fmaxf(a, b);
    __syncthreads();
    for (int o = 128; o > 0; o >>= 1) {
        if (t < o) red[t] = fmaxf(red[t], red[t + o]);
        __syncthreads();
    }
    float mx = red[0];
    __syncthreads();
    float ea = __expf(a - mx), eb = __expf(b - mx);
    red[t] = ea + eb;
    __syncthreads();
    for (int o = 128; o > 0; o >>= 1) {
        if (t < o) red[t] += red[t + o];
        __syncthreads();
    }
    float inv = 1.0f / red[0];
    P[r * 512 + t] = f2b(ea * inv);
    P[r * 512 + t + 256] = f2b(eb * inv);
}

// ---------------------------------------------------------------------------
// out = LN(Xa + Xb) * g + be ; Xa dtype AF (1=f32), Xb dtype BF, out OF
// ---------------------------------------------------------------------------
template<int AF, int BF, int OF>
__global__ __launch_bounds__(256) void ln_add_kernel(
    const void* __restrict__ Xa, const void* __restrict__ Xb,
    const float* __restrict__ g, const float* __restrict__ be,
    void* __restrict__ Out)
{
    const long r = blockIdx.x;
    int t = threadIdx.x;
    float v[3]; float sm = 0.f, s2 = 0.f;
#pragma unroll
    for (int e = 0; e < 3; e++) {
        long c = r * 768 + t + e * 256;
        float xa = AF ? ((const float*)Xa)[c] : b2f(((const u16*)Xa)[c]);
        float xb = BF ? ((const float*)Xb)[c] : b2f(((const u16*)Xb)[c]);
        float x = xa + xb;
        v[e] = x; sm += x; s2 += x * x;
    }
    __shared__ float r1[256], r2[256];
    r1[t] = sm; r2[t] = s2;
    __syncthreads();
    for (int o = 128; o > 0; o >>= 1) {
        if (t < o) { r1[t] += r1[t + o]; r2[t] += r2[t + o]; }
        __syncthreads();
    }
    float mean = r1[0] * (1.0f / 768.0f);
    float var  = r2[0] * (1.0f / 768.0f) - mean * mean;
    float rstd = rsqrtf(var + LN_EPS);
#pragma unroll
    for (int e = 0; e < 3; e++) {
        int c = t + e * 256;
        float o = (v[e] - mean) * rstd * g[c] + be[c];
        if (OF) ((float*)Out)[r * 768 + c] = o;
        else    ((u16*)Out)[r * 768 + c] = f2b(o);
    }
}

// ---------------------------------------------------------------------------
// Fused double-LN: y(f32) = LN2( X + LN1(A + B) ); also writes ybf (bf16)
// ---------------------------------------------------------------------------
__global__ __launch_bounds__(256) void ln_ln_kernel(
    const u16* __restrict__ A, const u16* __restrict__ B,
    const float* __restrict__ X,
    const float* __restrict__ g1, const float* __restrict__ be1,
    const float* __restrict__ g2, const float* __restrict__ be2,
    float* __restrict__ Out, u16* __restrict__ Outb)
{
    const long r = blockIdx.x;
    int t = threadIdx.x;
    __shared__ float r1[256], r2[256];

    float u[3]; float sm = 0.f, s2 = 0.f;
#pragma unroll
    for (int e = 0; e < 3; e++) {
        long c = r * 768 + t + e * 256;
        float x = b2f(A[c]) + b2f(B[c]);
        u[e] = x; sm += x; s2 += x * x;
    }
    r1[t] = sm; r2[t] = s2;
    __syncthreads();
    for (int o = 128; o > 0; o >>= 1) {
        if (t < o) { r1[t] += r1[t + o]; r2[t] += r2[t + o]; }
        __syncthreads();
    }
    float mean1 = r1[0] * (1.0f / 768.0f);
    float var1  = r2[0] * (1.0f / 768.0f) - mean1 * mean1;
    float rstd1 = rsqrtf(var1 + LN_EPS);
    __syncthreads();

    float w[3]; sm = 0.f; s2 = 0.f;
#pragma unroll
    for (int e = 0; e < 3; e++) {
        int c = t + e * 256;
        float tv = (u[e] - mean1) * rstd1 * g1[c] + be1[c];
        float wv = X[r * 768 + c] + tv;
        w[e] = wv; sm += wv; s2 += wv * wv;
    }
    r1[t] = sm; r2[t] = s2;
    __syncthreads();
    for (int o = 128; o > 0; o >>= 1) {
        if (t < o) { r1[t] += r1[t + o]; r2[t] += r2[t + o]; }
        __syncthreads();
    }
    float mean2 = r1[0] * (1.0f / 768.0f);
    float var2  = r2[0] * (1.0f / 768.0f) - mean2 * mean2;
    float rstd2 = rsqrtf(var2 + LN_EPS);
#pragma unroll
    for (int e = 0; e < 3; e++) {
        int c = t + e * 256;
        float o = (w[e] - mean2) * rstd2 * g2[c] + be2[c];
        Out[r * 768 + c] = o;
        Outb[r * 768 + c] = f2b(o);
    }
}

// ---------------------------------------------------------------------------
// Col attention for one 16-head group. Slices: [h'][l][s*12+c].
// Block = (h', l), 64 threads; thread i = query S-row.
// ---------------------------------------------------------------------------
__global__ __launch_bounds__(64) void col_attn_kernel(
    const u16* __restrict__ qc, const u16* __restrict__ kc,
    const u16* __restrict__ vc, u16* __restrict__ Out, int hbase)
{
    const int hh = blockIdx.x >> 9;
    const int l  = blockIdx.x & 511;
    const int i  = threadIdx.x;
    const long base = ((long)hh * 512 + l) * 768;
    __shared__ float Ks[64][12];
    __shared__ float Vs[64][12];
    float q[12];
#pragma unroll
    for (int c = 0; c < 12; c++) {
        q[c] = b2f(qc[base + i * 12 + c]);
        Ks[i][c] = b2f(kc[base + i * 12 + c]);
        Vs[i][c] = b2f(vc[base + i * 12 + c]);
    }
    __syncthreads();
    float sc[64];
#pragma unroll
    for (int j = 0; j < 64; j++) {
        float a = 0.f;
#pragma unroll
        for (int c = 0; c < 12; c++) a += q[c] * Ks[j][c];
        sc[j] = a;
    }
    float m = sc[0];
#pragma unroll
    for (int j = 1; j < 64; j++) m = fmaxf(m, sc[j]);
    float sum = 0.f;
#pragma unroll
    for (int j = 0; j < 64; j++) { sc[j] = __expf(sc[j] - m); sum += sc[j]; }
    float inv = 1.0f / sum;
    float o[12];
#pragma unroll
    for (int c = 0; c < 12; c++) o[c] = 0.f;
#pragma unroll
    for (int j = 0; j < 64; j++) {
        float p = sc[j] * inv;
#pragma unroll
        for (int c = 0; c < 12; c++) o[c] += p * Vs[j][c];
    }
    u16* op = Out + ((long)i * 512 + l) * 768 + hbase + hh * 12;
#pragma unroll
    for (int c = 0; c < 12; c++) op[c] = f2b(o[c]);
}

// ---------------------------------------------------------------------------
extern "C" void kernel_launch(void* const* d_in, const int* in_sizes, int n_in,
                              void* d_out, int out_size, void* d_ws, size_t ws_size,
                              hipStream_t stream)
{
    (void)in_sizes; (void)n_in; (void)out_size; (void)ws_size;

    const float* x     = (const float*)d_in[0];
    const float* w_row = (const float*)d_in[1];
    const float* b_row = (const float*)d_in[2];
    const float* w_col = (const float*)d_in[3];
    const float* b_col = (const float*)d_in[4];
    const float* g_a1  = (const float*)d_in[5];
    const float* be_a1 = (const float*)d_in[6];
    const float* g_a2  = (const float*)d_in[7];
    const float* be_a2 = (const float*)d_in[8];
    const float* w1    = (const float*)d_in[9];
    const float* b1f   = (const float*)d_in[10];
    const float* w2    = (const float*)d_in[11];
    const float* b2f_  = (const float*)d_in[12];
    const float* g_n1  = (const float*)d_in[13];
    const float* be_n1 = (const float*)d_in[14];
    const float* g_n2  = (const float*)d_in[15];
    const float* be_n2 = (const float*)d_in[16];
    float* outp = (float*)d_out;

    // ---- workspace layout (~172 MiB; matches R3/R4 footprint) ----
    char* wp = (char*)d_ws;
    auto alloc = [&](size_t bytes) -> void* {
        void* p = (void*)wp;
        wp += (bytes + 255) & ~(size_t)255;
        return p;
    };
    u16*   wPqk   = (u16*)alloc((size_t)1536 * 768 * 2);        // 2.25 MiB
    u16*   wPv    = (u16*)alloc((size_t)768 * 768 * 2);         // 1.13 MiB
    u16*   wPcol  = (u16*)alloc((size_t)2304 * 768 * 2);        // 3.38 MiB
    u16*   w1T    = (u16*)alloc((size_t)3072 * 768 * 2);        // 4.5 MiB
    u16*   w2T    = (u16*)alloc((size_t)768 * 3072 * 2);        // 4.5 MiB
    u16*   bufA   = (u16*)alloc((size_t)32768 * 768 * 2);       // 48 MiB: rowout/colout/ffb
    u16*   bufB   = (u16*)alloc((size_t)32768 * 768 * 2);       // 48 MiB: xb -> out1 -> ybf
    u16*   qkvg   = (u16*)alloc((size_t)3 * 16 * 512 * 768 * 2);// 36 MiB: Q|K|V group
    float* scores = (float*)alloc((size_t)16 * 512 * 512 * 4);  // 16 MiB
    u16*   probs  = (u16*)alloc((size_t)16 * 512 * 512 * 2);    // 8 MiB
    u16*   hidden = qkvg;    // alias: qkvg+scores dead during FFN (48 MiB)
    u16*   xb     = bufB;    // bf16 x; dead before out1 is written
    u16*   ybf    = bufB;    // bf16 y; out1 dead when ln_ln runs
    float* y      = outp;    // f32 y in d_out until final in-place LN

    // ---- weight packing (f32 -> bf16) ----
    pack_qk_kernel<<<dim3(48, 24), 256, 0, stream>>>(w_row, wPqk);
    pack_v_kernel<<<dim3(24, 24), 256, 0, stream>>>(w_row, wPv);
    qkv_pack_kernel<<<dim3(72, 24), 256, 0, stream>>>(w_col, wPcol);
    transpose_kernel<<<dim3(96, 24), 256, 0, stream>>>(w1, w1T, 768, 3072);
    transpose_kernel<<<dim3(24, 96), 256, 0, stream>>>(w2, w2T, 3072, 768);
    cast_kernel<<<12288, 256, 0, stream>>>(x, xb);

    // ---- row (tied) attention, 4 groups of 16 heads ----
    for (int hg = 0; hg < 4; hg++) {
        // Q,K (N=384, s-major, dense head-major writes)
        gemm_dma<192, 8, 0, 1, 1><<<dim3(2, 256), 256, 0, stream>>>(
            xb, wPqk + (long)hg * 384 * 768, b_row, qkvg,
            384, 768, 0, 0, 0, hg * 192);
        // V (N=192, s-blocked, dense V^T writes)
        gemm_dma<192, 3, 0, 1, 0><<<dim3(1, 256), 256, 0, stream>>>(
            xb, wPv + (long)hg * 192 * 768, b_row, qkvg + 2 * REG,
            192, 768, 0, 0, 0, 1536 + hg * 192);
        // scores = Q @ K^T (batched over 16 heads)
        gemm_dma<128, 1, 0, 0, 0><<<dim3(4, 4, 16), 256, 0, stream>>>(
            qkvg, qkvg + REG, nullptr, scores,
            512, 768, (long)512 * 768, (long)512 * 768, (long)512 * 512, 0);
        softmax_kernel<<<8192, 256, 0, stream>>>(scores, probs);
        // rowout = P @ V^T^T (batched over 16 heads)
        gemm_dma<128, 4, 0, 0, 0><<<dim3(6, 4, 16), 256, 0, stream>>>(
            probs, qkvg + 2 * REG, nullptr, bufA,
            768, 512, (long)512 * 512, (long)768 * 512, 0, hg * 192);
    }
    // out1 = LN(x + rowout)   (xb dead from here; bufB becomes out1)
    ln_add_kernel<1, 0, 0><<<32768, 256, 0, stream>>>(x, bufA, g_a1, be_a1, bufB);

    // ---- col attention, 4 groups of 16 heads ----
    for (int hg = 0; hg < 4; hg++) {
        gemm_dma<192, 9, 0, 1, 1><<<dim3(3, 256), 256, 0, stream>>>(
            bufB, wPcol + (long)hg * 576 * 768, b_col, qkvg,
            576, 768, 0, 0, 0, hg * 192);
        col_attn_kernel<<<8192, 64, 0, stream>>>(
            qkvg, qkvg + REG, qkvg + 2 * REG, bufA, hg * 192);
    }
    // y = LN(x + LN(out1 + colout)) -> d_out (f32) + ybf (bf16, row-local alias)
    ln_ln_kernel<<<32768, 256, 0, stream>>>(
        bufB, bufA, x, g_a2, be_a2, g_n1, be_n1, y, ybf);

    // ---- FFN, 4 chunks of 8192 rows (hidden overlays qkvg+scores) ----
    for (int mc = 0; mc < 4; mc++) {
        const long off = (long)mc * 8192 * 768;
        gemm_dma<192, 0, 1, 1, 0><<<dim3(16, 64), 256, 0, stream>>>(
            ybf + off, w1T, b1f, hidden, 3072, 768, 0, 0, 0, 0);
        gemm_dma<192, 0, 0, 1, 0><<<dim3(4, 64), 256, 0, stream>>>(
            hidden, w2T, b2f_, bufA + off, 768, 3072, 0, 0, 0, 0);
    }
    // final: out = LN(y + ffb), in-place over d_out (per-row, block-local)
    ln_add_kernel<1, 0, 1><<<32768, 256, 0, stream>>>(y, bufA, g_n2, be_n2, outp);
}